// Round 1
// baseline (1973.316 us; speedup 1.0000x reference)
//
#include <hip/hip_runtime.h>

// Problem constants
#define BATCH 4
#define SEQ   2048
#define CDIM  1024
#define NHEAD 16
#define HDIM  64   // CDIM / NHEAD

// ---------------------------------------------------------------------------
// Tiled fp32 GEMM, 128x128 tile, BK=16, 256 threads, 8x8 micro-tile.
// ---------------------------------------------------------------------------
#define TILE 128
#define BK   16

// QKV projection: x[8192,1024] @ W_attn[1024,3072] + b_attn,
// scattered into Q/K/V with layout [B,H,T,D].
__global__ __launch_bounds__(256) void qkv_gemm_kernel(
    const float* __restrict__ A,    // x  [M=8192, K=1024]
    const float* __restrict__ B,    // W_attn [K=1024, N=3072]
    const float* __restrict__ bias, // [3072]
    float* __restrict__ Qo, float* __restrict__ Ko, float* __restrict__ Vo)
{
    const int M = BATCH * SEQ;      // 8192
    const int N = 3 * CDIM;         // 3072
    const int K = CDIM;             // 1024

    __shared__ float As[BK][TILE + 4];
    __shared__ float Bs[BK][TILE + 4];

    const int m0 = blockIdx.y * TILE;
    const int n0 = blockIdx.x * TILE;
    const int tid = threadIdx.x;
    const int tr = tid >> 4;   // 0..15 (row group)
    const int tc = tid & 15;   // 0..15 (col group)

    float acc[8][8] = {};

    for (int k0 = 0; k0 < K; k0 += BK) {
        // A tile (128 rows x 16 k), store transposed As[k][m]
        #pragma unroll
        for (int i = 0; i < 2; ++i) {
            int lin = i * 256 + tid;          // 0..511
            int row = lin >> 2;               // 0..127
            int kc  = (lin & 3) << 2;         // 0,4,8,12
            float4 a4 = *(const float4*)(A + (size_t)(m0 + row) * K + k0 + kc);
            As[kc + 0][row] = a4.x; As[kc + 1][row] = a4.y;
            As[kc + 2][row] = a4.z; As[kc + 3][row] = a4.w;
        }
        // B tile (16 k x 128 n), natural Bs[k][n]
        #pragma unroll
        for (int i = 0; i < 2; ++i) {
            int lin = i * 256 + tid;
            int kr = lin >> 5;                // 0..15
            int nc = (lin & 31) << 2;         // 0..124
            *(float4*)(&Bs[kr][nc]) =
                *(const float4*)(B + (size_t)(k0 + kr) * N + n0 + nc);
        }
        __syncthreads();

        #pragma unroll
        for (int k = 0; k < BK; ++k) {
            float a[8], b[8];
            *(float4*)(a)     = *(float4*)(&As[k][tr * 8]);
            *(float4*)(a + 4) = *(float4*)(&As[k][tr * 8 + 4]);
            *(float4*)(b)     = *(float4*)(&Bs[k][tc * 8]);
            *(float4*)(b + 4) = *(float4*)(&Bs[k][tc * 8 + 4]);
            #pragma unroll
            for (int i = 0; i < 8; ++i)
                #pragma unroll
                for (int j = 0; j < 8; ++j)
                    acc[i][j] = fmaf(a[i], b[j], acc[i][j]);
        }
        __syncthreads();
    }

    // Epilogue: +bias, scatter to [B,H,T,D]. N-tile (128) always lies in one
    // of the q/k/v thirds (1024 % 128 == 0).
    #pragma unroll
    for (int ri = 0; ri < 8; ++ri) {
        int m = m0 + tr * 8 + ri;
        int b = m >> 11;            // /2048
        int t = m & 2047;
        #pragma unroll
        for (int g = 0; g < 2; ++g) {
            int j0 = n0 + tc * 8 + g * 4;
            int which = j0 >> 10;       // 0=q 1=k 2=v
            int c1 = j0 & 1023;
            int h  = c1 >> 6;
            int d0 = c1 & 63;
            float* outw = (which == 0) ? Qo : (which == 1) ? Ko : Vo;
            float4 v;
            v.x = acc[ri][g * 4 + 0] + bias[j0 + 0];
            v.y = acc[ri][g * 4 + 1] + bias[j0 + 1];
            v.z = acc[ri][g * 4 + 2] + bias[j0 + 2];
            v.w = acc[ri][g * 4 + 3] + bias[j0 + 3];
            *(float4*)(outw + ((size_t)((b * NHEAD + h) * SEQ + t)) * HDIM + d0) = v;
        }
    }
}

// Output projection: Y[8192,1024] @ W_proj[1024,1024] + b_proj -> out [B,T,C]
__global__ __launch_bounds__(256) void proj_gemm_kernel(
    const float* __restrict__ A,    // Y [8192,1024]
    const float* __restrict__ B,    // W_proj [1024,1024]
    const float* __restrict__ bias, // [1024]
    float* __restrict__ out)
{
    const int N = CDIM, K = CDIM;

    __shared__ float As[BK][TILE + 4];
    __shared__ float Bs[BK][TILE + 4];

    const int m0 = blockIdx.y * TILE;
    const int n0 = blockIdx.x * TILE;
    const int tid = threadIdx.x;
    const int tr = tid >> 4;
    const int tc = tid & 15;

    float acc[8][8] = {};

    for (int k0 = 0; k0 < K; k0 += BK) {
        #pragma unroll
        for (int i = 0; i < 2; ++i) {
            int lin = i * 256 + tid;
            int row = lin >> 2;
            int kc  = (lin & 3) << 2;
            float4 a4 = *(const float4*)(A + (size_t)(m0 + row) * K + k0 + kc);
            As[kc + 0][row] = a4.x; As[kc + 1][row] = a4.y;
            As[kc + 2][row] = a4.z; As[kc + 3][row] = a4.w;
        }
        #pragma unroll
        for (int i = 0; i < 2; ++i) {
            int lin = i * 256 + tid;
            int kr = lin >> 5;
            int nc = (lin & 31) << 2;
            *(float4*)(&Bs[kr][nc]) =
                *(const float4*)(B + (size_t)(k0 + kr) * N + n0 + nc);
        }
        __syncthreads();

        #pragma unroll
        for (int k = 0; k < BK; ++k) {
            float a[8], b[8];
            *(float4*)(a)     = *(float4*)(&As[k][tr * 8]);
            *(float4*)(a + 4) = *(float4*)(&As[k][tr * 8 + 4]);
            *(float4*)(b)     = *(float4*)(&Bs[k][tc * 8]);
            *(float4*)(b + 4) = *(float4*)(&Bs[k][tc * 8 + 4]);
            #pragma unroll
            for (int i = 0; i < 8; ++i)
                #pragma unroll
                for (int j = 0; j < 8; ++j)
                    acc[i][j] = fmaf(a[i], b[j], acc[i][j]);
        }
        __syncthreads();
    }

    #pragma unroll
    for (int ri = 0; ri < 8; ++ri) {
        int m = m0 + tr * 8 + ri;
        #pragma unroll
        for (int g = 0; g < 2; ++g) {
            int j0 = n0 + tc * 8 + g * 4;
            float4 v;
            v.x = acc[ri][g * 4 + 0] + bias[j0 + 0];
            v.y = acc[ri][g * 4 + 1] + bias[j0 + 1];
            v.z = acc[ri][g * 4 + 2] + bias[j0 + 2];
            v.w = acc[ri][g * 4 + 3] + bias[j0 + 3];
            *(float4*)(out + (size_t)m * N + j0) = v;
        }
    }
}

// ---------------------------------------------------------------------------
// Flash-style attention (non-causal), fp32.
// One workgroup per (b,h, 64-row q block). 64x64 K/V tiles, online softmax.
// Thread map for both 64x64x64 matmuls: tm=(tid/16)*4 rows, tn=(tid%16)*4 cols.
// ---------------------------------------------------------------------------
__global__ __launch_bounds__(256) void attn_kernel(
    const float* __restrict__ Q, const float* __restrict__ K,
    const float* __restrict__ V, float* __restrict__ Y)
{
    __shared__ float Qt[64][68];   // [d][qrow]
    __shared__ float Kt[64][68];   // [d][krow]
    __shared__ float Vs[64][68];   // [krow][d]
    __shared__ float St[64][68];   // P transposed: [k][qrow]

    const int qb = blockIdx.x;         // 0..31
    const int bh = blockIdx.y;         // 0..63
    const int b  = bh >> 4;
    const int h  = bh & 15;
    const size_t base = (size_t)bh * SEQ * HDIM;

    const int tid = threadIdx.x;
    const int tm = (tid >> 4) * 4;     // q-row group
    const int tn = (tid & 15) * 4;     // col group (k-col for scores, d for PV)

    // Load Q tile transposed: Qt[d][row]
    #pragma unroll
    for (int i = 0; i < 4; ++i) {
        int lin = i * 256 + tid;           // 0..1023
        int row = lin >> 4;                // 0..63
        int dc  = (lin & 15) << 2;         // 0..60
        float4 v = *(const float4*)(Q + base + (size_t)(qb * 64 + row) * HDIM + dc);
        Qt[dc + 0][row] = v.x; Qt[dc + 1][row] = v.y;
        Qt[dc + 2][row] = v.z; Qt[dc + 3][row] = v.w;
    }

    float O[4][4] = {};
    float mrun[4], lrun[4];
    #pragma unroll
    for (int i = 0; i < 4; ++i) { mrun[i] = -1e30f; lrun[i] = 0.0f; }
    const float scale = 0.125f;    // 1/sqrt(64)

    for (int kb = 0; kb < SEQ / 64; ++kb) {
        __syncthreads();   // previous PV done before overwriting Kt/Vs/St
        #pragma unroll
        for (int i = 0; i < 4; ++i) {
            int lin = i * 256 + tid;
            int row = lin >> 4;
            int dc  = (lin & 15) << 2;
            float4 v = *(const float4*)(K + base + (size_t)(kb * 64 + row) * HDIM + dc);
            Kt[dc + 0][row] = v.x; Kt[dc + 1][row] = v.y;
            Kt[dc + 2][row] = v.z; Kt[dc + 3][row] = v.w;
            float4 w = *(const float4*)(V + base + (size_t)(kb * 64 + row) * HDIM + dc);
            *(float4*)(&Vs[row][dc]) = w;
        }
        __syncthreads();

        // scores S[tm..+3][tn..+3] = Q(rows) . K(cols)
        float s[4][4] = {};
        #pragma unroll 8
        for (int d = 0; d < 64; ++d) {
            float4 a4 = *(float4*)(&Qt[d][tm]);
            float4 b4 = *(float4*)(&Kt[d][tn]);
            float a[4] = {a4.x, a4.y, a4.z, a4.w};
            float c[4] = {b4.x, b4.y, b4.z, b4.w};
            #pragma unroll
            for (int i = 0; i < 4; ++i)
                #pragma unroll
                for (int j = 0; j < 4; ++j)
                    s[i][j] = fmaf(a[i], c[j], s[i][j]);
        }

        // online softmax, per q-row; 16 threads share a row-group (consecutive
        // lanes), reduce with shfl_xor over 16 lanes.
        #pragma unroll
        for (int i = 0; i < 4; ++i) {
            float s0 = s[i][0] * scale, s1 = s[i][1] * scale;
            float s2 = s[i][2] * scale, s3 = s[i][3] * scale;
            float mloc = fmaxf(fmaxf(s0, s1), fmaxf(s2, s3));
            #pragma unroll
            for (int off = 1; off < 16; off <<= 1)
                mloc = fmaxf(mloc, __shfl_xor(mloc, off));
            float mnew  = fmaxf(mrun[i], mloc);
            float alpha = __expf(mrun[i] - mnew);
            float p0 = __expf(s0 - mnew);
            float p1 = __expf(s1 - mnew);
            float p2 = __expf(s2 - mnew);
            float p3 = __expf(s3 - mnew);
            float ls = (p0 + p1) + (p2 + p3);
            #pragma unroll
            for (int off = 1; off < 16; off <<= 1)
                ls += __shfl_xor(ls, off);
            lrun[i] = lrun[i] * alpha + ls;
            mrun[i] = mnew;
            O[i][0] *= alpha; O[i][1] *= alpha; O[i][2] *= alpha; O[i][3] *= alpha;
            St[tn + 0][tm + i] = p0;
            St[tn + 1][tm + i] = p1;
            St[tn + 2][tm + i] = p2;
            St[tn + 3][tm + i] = p3;
        }
        __syncthreads();

        // O[rows tm..+3][d tn..+3] += P . V
        #pragma unroll 8
        for (int k2 = 0; k2 < 64; ++k2) {
            float4 a4 = *(float4*)(&St[k2][tm]);
            float4 b4 = *(float4*)(&Vs[k2][tn]);
            float a[4] = {a4.x, a4.y, a4.z, a4.w};
            float c[4] = {b4.x, b4.y, b4.z, b4.w};
            #pragma unroll
            for (int i = 0; i < 4; ++i)
                #pragma unroll
                for (int j = 0; j < 4; ++j)
                    O[i][j] = fmaf(a[i], c[j], O[i][j]);
        }
    }

    // normalize and write Y[b, t, h*64 + d]  (Y is [B,T,C] for the proj GEMM)
    const int t0 = qb * 64;
    #pragma unroll
    for (int i = 0; i < 4; ++i) {
        float inv = 1.0f / lrun[i];
        float4 v;
        v.x = O[i][0] * inv; v.y = O[i][1] * inv;
        v.z = O[i][2] * inv; v.w = O[i][3] * inv;
        *(float4*)(Y + ((size_t)(b * SEQ + t0 + tm + i)) * CDIM + h * HDIM + tn) = v;
    }
}

extern "C" void kernel_launch(void* const* d_in, const int* in_sizes, int n_in,
                              void* d_out, int out_size, void* d_ws, size_t ws_size,
                              hipStream_t stream) {
    const float* x      = (const float*)d_in[0];
    const float* W_attn = (const float*)d_in[1];
    const float* b_attn = (const float*)d_in[2];
    const float* W_proj = (const float*)d_in[3];
    const float* b_proj = (const float*)d_in[4];
    float* out = (float*)d_out;

    const size_t elems = (size_t)BATCH * SEQ * CDIM;   // 8388608
    float* Qb = (float*)d_ws;
    float* Kb = Qb + elems;
    float* Vb = Kb + elems;
    float* Yb = Vb + elems;

    // 1) QKV projection -> Q/K/V [B,H,T,D]
    {
        dim3 grid(3 * CDIM / TILE, BATCH * SEQ / TILE);   // (24, 64)
        qkv_gemm_kernel<<<grid, 256, 0, stream>>>(x, W_attn, b_attn, Qb, Kb, Vb);
    }
    // 2) flash attention -> Y [B,T,C]
    {
        dim3 grid(SEQ / 64, BATCH * NHEAD);               // (32, 64)
        attn_kernel<<<grid, 256, 0, stream>>>(Qb, Kb, Vb, Yb);
    }
    // 3) output projection -> out [B,T,C]
    {
        dim3 grid(CDIM / TILE, BATCH * SEQ / TILE);       // (8, 64)
        proj_gemm_kernel<<<grid, 256, 0, stream>>>(Yb, W_proj, b_proj, out);
    }
}

// Round 2
// 508.720 us; speedup vs baseline: 3.8790x; 3.8790x over previous
//
#include <hip/hip_runtime.h>

#define BATCH 4
#define SEQ   2048
#define CDIM  1024
#define NHEAD 16
#define HDIM  64
#define BH    (BATCH * NHEAD)   // 64
#define MROWS (BATCH * SEQ)     // 8192

typedef __attribute__((ext_vector_type(8))) short  short8;
typedef __attribute__((ext_vector_type(4))) float  floatx4;

#define MFMA_BF16(a, b, c) __builtin_amdgcn_mfma_f32_16x16x32_bf16((a), (b), (c), 0, 0, 0)

// async global->LDS, 16B per lane. LDS dest must be contiguous in lane order.
#define GLOAD16(g, l) __builtin_amdgcn_global_load_lds( \
    (__attribute__((address_space(1))) void*)(g),       \
    (__attribute__((address_space(3))) void*)(l), 16, 0, 0)

__device__ __forceinline__ unsigned short f2bf(float f) {
    union { float f; unsigned u; } v; v.f = f;
    unsigned u = v.u;
    return (unsigned short)((u + 0x7FFFu + ((u >> 16) & 1u)) >> 16);
}

// ---------------------------------------------------------------------------
// fp32 -> bf16 elementwise convert (x). 4 elems/thread.
// ---------------------------------------------------------------------------
__global__ __launch_bounds__(256) void conv_bf16_kernel(
    const float* __restrict__ in, unsigned short* __restrict__ out)
{
    int i = (blockIdx.x * 256 + threadIdx.x) * 4;
    float4 v = *(const float4*)(in + i);
    ushort4 o;
    o.x = f2bf(v.x); o.y = f2bf(v.y); o.z = f2bf(v.z); o.w = f2bf(v.w);
    *(ushort4*)(out + i) = o;
}

// ---------------------------------------------------------------------------
// fp32 [K][N] -> bf16 transposed [N][K] (weights). 64x64 LDS tiles.
// ---------------------------------------------------------------------------
__global__ __launch_bounds__(256) void conv_wt_kernel(
    const float* __restrict__ in, unsigned short* __restrict__ out, int K, int N)
{
    __shared__ float T[64][68];
    const int k0 = blockIdx.y * 64, n0 = blockIdx.x * 64;
    const int tid = threadIdx.x;
    const int r = tid >> 4, c4 = (tid & 15) * 4;
    #pragma unroll
    for (int i = 0; i < 4; ++i) {
        int row = r + i * 16;
        float4 v = *(const float4*)(in + (size_t)(k0 + row) * N + n0 + c4);
        T[row][c4 + 0] = v.x; T[row][c4 + 1] = v.y;
        T[row][c4 + 2] = v.z; T[row][c4 + 3] = v.w;
    }
    __syncthreads();
    #pragma unroll
    for (int i = 0; i < 4; ++i) {
        int nrow = r + i * 16;
        ushort4 o;
        o.x = f2bf(T[c4 + 0][nrow]); o.y = f2bf(T[c4 + 1][nrow]);
        o.z = f2bf(T[c4 + 2][nrow]); o.w = f2bf(T[c4 + 3][nrow]);
        *(ushort4*)(out + (size_t)(n0 + nrow) * K + k0 + c4) = o;
    }
}

// ---------------------------------------------------------------------------
// MFMA GEMM, m97 structure: 128x128 tile, BK=32, 256 thr = 4 waves (2x2),
// each wave 64x64 = 4x4 tiles of 16x16x32. A row-major [M][K] bf16,
// Bt row-major [N][K] bf16 (i.e. B transposed). fp32 accum.
// QKV variant: epilogue +bias, cast bf16, scatter Q,K:[BH][T][D], V:[BH][D][T].
// ---------------------------------------------------------------------------
__global__ __launch_bounds__(256) void qkv_mfma_kernel(
    const unsigned short* __restrict__ A,    // xb [8192][1024]
    const unsigned short* __restrict__ Bt,   // Wat [3072][1024]
    const float* __restrict__ bias,          // [3072]
    unsigned short* __restrict__ Qo,         // [BH][T][64]
    unsigned short* __restrict__ Ko,         // [BH][T][64]
    unsigned short* __restrict__ Vo)         // [BH][64][T]
{
    const int K = CDIM;
    __shared__ __align__(16) unsigned short As[128 * 32];
    __shared__ __align__(16) unsigned short Bs[128 * 32];

    const int tid = threadIdx.x;
    const int m0 = blockIdx.y * 128, n0 = blockIdx.x * 128;
    const int w = tid >> 6, lane = tid & 63;
    const int wm = (w >> 1) * 64, wn = (w & 1) * 64;
    const int lm = lane & 15, kg = lane >> 4;

    floatx4 acc[4][4];
    const floatx4 zf = {0.f, 0.f, 0.f, 0.f};
    #pragma unroll
    for (int mt = 0; mt < 4; ++mt)
        #pragma unroll
        for (int nt = 0; nt < 4; ++nt) acc[mt][nt] = zf;

    #pragma unroll 1
    for (int k0 = 0; k0 < K; k0 += 32) {
        __syncthreads();
        #pragma unroll
        for (int i = 0; i < 2; ++i) {
            int ci = i * 256 + tid;                 // 0..511
            GLOAD16(A  + (size_t)(m0 + (ci >> 2)) * K + k0 + (ci & 3) * 8, As + ci * 8);
            GLOAD16(Bt + (size_t)(n0 + (ci >> 2)) * K + k0 + (ci & 3) * 8, Bs + ci * 8);
        }
        __syncthreads();
        short8 af[4], bf[4];
        #pragma unroll
        for (int t = 0; t < 4; ++t) {
            af[t] = *(const short8*)(As + (wm + t * 16 + lm) * 32 + kg * 8);
            bf[t] = *(const short8*)(Bs + (wn + t * 16 + lm) * 32 + kg * 8);
        }
        #pragma unroll
        for (int mt = 0; mt < 4; ++mt)
            #pragma unroll
            for (int nt = 0; nt < 4; ++nt)
                acc[mt][nt] = MFMA_BF16(af[mt], bf[nt], acc[mt][nt]);
    }

    // C layout per 16x16 tile: col = lane&15, row = (lane>>4)*4 + reg
    #pragma unroll
    for (int nt = 0; nt < 4; ++nt) {
        int col = n0 + wn + nt * 16 + lm;       // 0..3071 (third is block-uniform)
        float bv = bias[col];
        int which = col >> 10;
        int c1 = col & 1023;
        int h = c1 >> 6, d = c1 & 63;
        #pragma unroll
        for (int mt = 0; mt < 4; ++mt) {
            int mbase = m0 + wm + mt * 16 + kg * 4;
            int b = mbase >> 11;
            int t = mbase & 2047;               // t..t+3 contiguous
            int bh = b * NHEAD + h;
            if (which == 2) {
                ushort4 o;
                o.x = f2bf(acc[mt][nt][0] + bv);
                o.y = f2bf(acc[mt][nt][1] + bv);
                o.z = f2bf(acc[mt][nt][2] + bv);
                o.w = f2bf(acc[mt][nt][3] + bv);
                *(ushort4*)(Vo + ((size_t)bh * 64 + d) * SEQ + t) = o;
            } else {
                unsigned short* dst = (which == 0) ? Qo : Ko;
                #pragma unroll
                for (int r = 0; r < 4; ++r)
                    dst[((size_t)bh * SEQ + t + r) * 64 + d] = f2bf(acc[mt][nt][r] + bv);
            }
        }
    }
}

// Proj variant: A = Yb [8192][1024] bf16, Bt = Wpt [1024][1024] bf16,
// out fp32 [8192][1024] + bias.
__global__ __launch_bounds__(256) void proj_mfma_kernel(
    const unsigned short* __restrict__ A,
    const unsigned short* __restrict__ Bt,
    const float* __restrict__ bias,
    float* __restrict__ out)
{
    const int K = CDIM;
    __shared__ __align__(16) unsigned short As[128 * 32];
    __shared__ __align__(16) unsigned short Bs[128 * 32];

    const int tid = threadIdx.x;
    const int m0 = blockIdx.y * 128, n0 = blockIdx.x * 128;
    const int w = tid >> 6, lane = tid & 63;
    const int wm = (w >> 1) * 64, wn = (w & 1) * 64;
    const int lm = lane & 15, kg = lane >> 4;

    floatx4 acc[4][4];
    const floatx4 zf = {0.f, 0.f, 0.f, 0.f};
    #pragma unroll
    for (int mt = 0; mt < 4; ++mt)
        #pragma unroll
        for (int nt = 0; nt < 4; ++nt) acc[mt][nt] = zf;

    #pragma unroll 1
    for (int k0 = 0; k0 < K; k0 += 32) {
        __syncthreads();
        #pragma unroll
        for (int i = 0; i < 2; ++i) {
            int ci = i * 256 + tid;
            GLOAD16(A  + (size_t)(m0 + (ci >> 2)) * K + k0 + (ci & 3) * 8, As + ci * 8);
            GLOAD16(Bt + (size_t)(n0 + (ci >> 2)) * K + k0 + (ci & 3) * 8, Bs + ci * 8);
        }
        __syncthreads();
        short8 af[4], bf[4];
        #pragma unroll
        for (int t = 0; t < 4; ++t) {
            af[t] = *(const short8*)(As + (wm + t * 16 + lm) * 32 + kg * 8);
            bf[t] = *(const short8*)(Bs + (wn + t * 16 + lm) * 32 + kg * 8);
        }
        #pragma unroll
        for (int mt = 0; mt < 4; ++mt)
            #pragma unroll
            for (int nt = 0; nt < 4; ++nt)
                acc[mt][nt] = MFMA_BF16(af[mt], bf[nt], acc[mt][nt]);
    }

    #pragma unroll
    for (int nt = 0; nt < 4; ++nt) {
        int col = n0 + wn + nt * 16 + lm;
        float bv = bias[col];
        #pragma unroll
        for (int mt = 0; mt < 4; ++mt) {
            int mbase = m0 + wm + mt * 16 + kg * 4;
            #pragma unroll
            for (int r = 0; r < 4; ++r)
                out[(size_t)(mbase + r) * CDIM + col] = acc[mt][nt][r] + bv;
        }
    }
}

// ---------------------------------------------------------------------------
// Flash attention, bf16 MFMA. Block = 256 thr = 4 waves; block handles
// (bh, 64 q-rows); wave w owns q-rows w*16..+15. KV swept in 64-col tiles.
// Q,K: [BH][T][64] bf16; V transposed: [BH][64][T] bf16. Out Y: [B][T][C] bf16.
// ---------------------------------------------------------------------------
__global__ __launch_bounds__(256) void attn_mfma_kernel(
    const unsigned short* __restrict__ Q,
    const unsigned short* __restrict__ Kk,
    const unsigned short* __restrict__ Vt,
    unsigned short* __restrict__ Y)
{
    __shared__ __align__(16) unsigned short Qs[64 * 64];
    __shared__ __align__(16) unsigned short Ks[64 * 64];
    __shared__ __align__(16) unsigned short Vs[64 * 64];   // [d][kcol]
    __shared__ __align__(16) unsigned short Ps[64 * 72];   // padded stride 72

    const int tid = threadIdx.x, w = tid >> 6, lane = tid & 63;
    const int lm = lane & 15, kg = lane >> 4;
    const int qb = blockIdx.x, bh = blockIdx.y;
    const size_t base = (size_t)bh * SEQ * 64;

    // stage Q tile [64][64]
    #pragma unroll
    for (int i = 0; i < 2; ++i) {
        int ci = i * 256 + tid;                  // row=ci>>3 (8 chunks/row), c8=ci&7
        GLOAD16(Q + base + (size_t)(qb * 64 + (ci >> 3)) * 64 + (ci & 7) * 8, Qs + ci * 8);
    }
    __syncthreads();
    short8 qf0 = *(const short8*)(Qs + (w * 16 + lm) * 64 + kg * 8);
    short8 qf1 = *(const short8*)(Qs + (w * 16 + lm) * 64 + 32 + kg * 8);

    const floatx4 zf = {0.f, 0.f, 0.f, 0.f};
    floatx4 O[4];
    #pragma unroll
    for (int nt = 0; nt < 4; ++nt) O[nt] = zf;
    float mrun[4], lrun[4];
    #pragma unroll
    for (int r = 0; r < 4; ++r) { mrun[r] = -1e30f; lrun[r] = 0.f; }

    #pragma unroll 1
    for (int kb = 0; kb < SEQ / 64; ++kb) {
        __syncthreads();
        #pragma unroll
        for (int i = 0; i < 2; ++i) {
            int ci = i * 256 + tid;
            GLOAD16(Kk + base + (size_t)(kb * 64 + (ci >> 3)) * 64 + (ci & 7) * 8, Ks + ci * 8);
            GLOAD16(Vt + base + (size_t)(ci >> 3) * SEQ + kb * 64 + (ci & 7) * 8, Vs + ci * 8);
        }
        __syncthreads();

        // scores: S[16 q x 64 k] = Q . K^T, 4 n-tiles x 2 k-chunks
        floatx4 s[4];
        #pragma unroll
        for (int nt = 0; nt < 4; ++nt) {
            s[nt] = zf;
            short8 b0 = *(const short8*)(Ks + (nt * 16 + lm) * 64 + kg * 8);
            short8 b1 = *(const short8*)(Ks + (nt * 16 + lm) * 64 + 32 + kg * 8);
            s[nt] = MFMA_BF16(qf0, b0, s[nt]);
            s[nt] = MFMA_BF16(qf1, b1, s[nt]);
        }
        #pragma unroll
        for (int nt = 0; nt < 4; ++nt) s[nt] = s[nt] * 0.125f;  // 1/sqrt(64)

        // online softmax; lane's rows r: qrow_local = w*16 + kg*4 + r
        float alpha[4];
        #pragma unroll
        for (int r = 0; r < 4; ++r) {
            float mv = fmaxf(fmaxf(s[0][r], s[1][r]), fmaxf(s[2][r], s[3][r]));
            mv = fmaxf(mv, __shfl_xor(mv, 1));
            mv = fmaxf(mv, __shfl_xor(mv, 2));
            mv = fmaxf(mv, __shfl_xor(mv, 4));
            mv = fmaxf(mv, __shfl_xor(mv, 8));
            float mnew = fmaxf(mrun[r], mv);
            alpha[r] = __expf(mrun[r] - mnew);
            mrun[r] = mnew;
            float p0 = __expf(s[0][r] - mnew);
            float p1 = __expf(s[1][r] - mnew);
            float p2 = __expf(s[2][r] - mnew);
            float p3 = __expf(s[3][r] - mnew);
            s[0][r] = p0; s[1][r] = p1; s[2][r] = p2; s[3][r] = p3;
            float ls = (p0 + p1) + (p2 + p3);
            ls += __shfl_xor(ls, 1);
            ls += __shfl_xor(ls, 2);
            ls += __shfl_xor(ls, 4);
            ls += __shfl_xor(ls, 8);
            lrun[r] = lrun[r] * alpha[r] + ls;
        }

        // P -> LDS bf16 (wave-private rows w*16..+15, stride 72)
        #pragma unroll
        for (int nt = 0; nt < 4; ++nt)
            #pragma unroll
            for (int r = 0; r < 4; ++r)
                Ps[(w * 16 + kg * 4 + r) * 72 + nt * 16 + lm] = f2bf(s[nt][r]);

        // rescale O
        #pragma unroll
        for (int nt = 0; nt < 4; ++nt)
            #pragma unroll
            for (int r = 0; r < 4; ++r)
                O[nt][r] *= alpha[r];

        __syncthreads();   // P write -> frag read ordering (and Vs stability)

        // PV: O[16 q x 64 d] += P . V ; A-frags from Ps, B-frags from Vs [d][k]
        short8 pf0 = *(const short8*)(Ps + (w * 16 + lm) * 72 + kg * 8);
        short8 pf1 = *(const short8*)(Ps + (w * 16 + lm) * 72 + 32 + kg * 8);
        #pragma unroll
        for (int nt = 0; nt < 4; ++nt) {
            short8 v0 = *(const short8*)(Vs + (nt * 16 + lm) * 64 + kg * 8);
            short8 v1 = *(const short8*)(Vs + (nt * 16 + lm) * 64 + 32 + kg * 8);
            O[nt] = MFMA_BF16(pf0, v0, O[nt]);
            O[nt] = MFMA_BF16(pf1, v1, O[nt]);
        }
    }

    // epilogue: Y[b][t][h*64 + d] bf16
    const int b = bh >> 4, h = bh & 15;
    #pragma unroll
    for (int r = 0; r < 4; ++r) {
        float inv = 1.f / lrun[r];
        int t = qb * 64 + w * 16 + kg * 4 + r;
        #pragma unroll
        for (int nt = 0; nt < 4; ++nt)
            Y[((size_t)(b * SEQ + t)) * CDIM + h * 64 + nt * 16 + lm] =
                f2bf(O[nt][r] * inv);
    }
}

extern "C" void kernel_launch(void* const* d_in, const int* in_sizes, int n_in,
                              void* d_out, int out_size, void* d_ws, size_t ws_size,
                              hipStream_t stream) {
    const float* x      = (const float*)d_in[0];
    const float* W_attn = (const float*)d_in[1];
    const float* b_attn = (const float*)d_in[2];
    const float* W_proj = (const float*)d_in[3];
    const float* b_proj = (const float*)d_in[4];
    float* out = (float*)d_out;

    // workspace layout (bf16 buffers)
    char* ws = (char*)d_ws;
    unsigned short* xb  = (unsigned short*)(ws);                      // 16.8 MB
    unsigned short* Wat = (unsigned short*)(ws + (size_t)16777216);   //  6.3 MB
    unsigned short* Wpt = (unsigned short*)(ws + (size_t)23068672);   //  2.1 MB
    unsigned short* Qb  = (unsigned short*)(ws + (size_t)25165824);   // 16.8 MB
    unsigned short* Kb  = (unsigned short*)(ws + (size_t)41943040);   // 16.8 MB
    unsigned short* Vtb = (unsigned short*)(ws + (size_t)58720256);   // 16.8 MB
    unsigned short* Yb  = (unsigned short*)(ws + (size_t)75497472);   // 16.8 MB

    // converts
    conv_bf16_kernel<<<dim3(MROWS * CDIM / 1024), 256, 0, stream>>>(x, xb);
    conv_wt_kernel<<<dim3(3 * CDIM / 64, CDIM / 64), 256, 0, stream>>>(
        W_attn, Wat, CDIM, 3 * CDIM);
    conv_wt_kernel<<<dim3(CDIM / 64, CDIM / 64), 256, 0, stream>>>(
        W_proj, Wpt, CDIM, CDIM);

    // QKV projection
    qkv_mfma_kernel<<<dim3(3 * CDIM / 128, MROWS / 128), 256, 0, stream>>>(
        xb, Wat, b_attn, Qb, Kb, Vtb);

    // attention
    attn_mfma_kernel<<<dim3(SEQ / 64, BH), 256, 0, stream>>>(Qb, Kb, Vtb, Yb);

    // output projection
    proj_mfma_kernel<<<dim3(CDIM / 128, MROWS / 128), 256, 0, stream>>>(
        Yb, Wpt, b_proj, out);
}

// Round 3
// 375.813 us; speedup vs baseline: 5.2508x; 1.3537x over previous
//
#include <hip/hip_runtime.h>

#define BATCH 4
#define SEQ   2048
#define CDIM  1024
#define NHEAD 16
#define HDIM  64
#define BH    (BATCH * NHEAD)   // 64
#define MROWS (BATCH * SEQ)     // 8192

typedef __attribute__((ext_vector_type(8))) short  short8;
typedef __attribute__((ext_vector_type(4))) float  floatx4;

#define MFMA_BF16(a, b, c) __builtin_amdgcn_mfma_f32_16x16x32_bf16((a), (b), (c), 0, 0, 0)

// async global->LDS, 16B per lane (GEMMs only; attn uses padded manual staging)
#define GLOAD16(g, l) __builtin_amdgcn_global_load_lds( \
    (__attribute__((address_space(1))) void*)(g),       \
    (__attribute__((address_space(3))) void*)(l), 16, 0, 0)

__device__ __forceinline__ unsigned short f2bf(float f) {
    union { float f; unsigned u; } v; v.f = f;
    unsigned u = v.u;
    return (unsigned short)((u + 0x7FFFu + ((u >> 16) & 1u)) >> 16);
}

__device__ __forceinline__ float fast_exp2(float x) {
#if __has_builtin(__builtin_amdgcn_exp2f)
    return __builtin_amdgcn_exp2f(x);
#else
    return exp2f(x);
#endif
}

// pack two fp32 -> two bf16 (round-nearest, ties away) in one dword
__device__ __forceinline__ unsigned pack_bf16(float a, float b) {
    union { float f; unsigned u; } ua, ub;
    ua.f = a; ub.f = b;
    return __builtin_amdgcn_perm(ub.u + 0x8000u, ua.u + 0x8000u, 0x07060302u);
}

// ---------------------------------------------------------------------------
// fp32 -> bf16 elementwise convert (x). 4 elems/thread.
// ---------------------------------------------------------------------------
__global__ __launch_bounds__(256) void conv_bf16_kernel(
    const float* __restrict__ in, unsigned short* __restrict__ out)
{
    int i = (blockIdx.x * 256 + threadIdx.x) * 4;
    float4 v = *(const float4*)(in + i);
    ushort4 o;
    o.x = f2bf(v.x); o.y = f2bf(v.y); o.z = f2bf(v.z); o.w = f2bf(v.w);
    *(ushort4*)(out + i) = o;
}

// ---------------------------------------------------------------------------
// fp32 [K][N] -> bf16 transposed [N][K] (weights). 64x64 LDS tiles.
// ---------------------------------------------------------------------------
__global__ __launch_bounds__(256) void conv_wt_kernel(
    const float* __restrict__ in, unsigned short* __restrict__ out, int K, int N)
{
    __shared__ float T[64][68];
    const int k0 = blockIdx.y * 64, n0 = blockIdx.x * 64;
    const int tid = threadIdx.x;
    const int r = tid >> 4, c4 = (tid & 15) * 4;
    #pragma unroll
    for (int i = 0; i < 4; ++i) {
        int row = r + i * 16;
        float4 v = *(const float4*)(in + (size_t)(k0 + row) * N + n0 + c4);
        T[row][c4 + 0] = v.x; T[row][c4 + 1] = v.y;
        T[row][c4 + 2] = v.z; T[row][c4 + 3] = v.w;
    }
    __syncthreads();
    #pragma unroll
    for (int i = 0; i < 4; ++i) {
        int nrow = r + i * 16;
        ushort4 o;
        o.x = f2bf(T[c4 + 0][nrow]); o.y = f2bf(T[c4 + 1][nrow]);
        o.z = f2bf(T[c4 + 2][nrow]); o.w = f2bf(T[c4 + 3][nrow]);
        *(ushort4*)(out + (size_t)(n0 + nrow) * K + k0 + c4) = o;
    }
}

// ---------------------------------------------------------------------------
// MFMA GEMM, 128x128 tile, BK=32, 256 thr = 4 waves (2x2), 16x16x32 bf16.
// QKV variant: +bias, Q pre-scaled by 0.125*log2(e) for exp2 softmax,
// scatter Q,K:[BH][T][D], V transposed:[BH][D][T].
// ---------------------------------------------------------------------------
__global__ __launch_bounds__(256) void qkv_mfma_kernel(
    const unsigned short* __restrict__ A,    // xb [8192][1024]
    const unsigned short* __restrict__ Bt,   // Wat [3072][1024]
    const float* __restrict__ bias,          // [3072]
    unsigned short* __restrict__ Qo,         // [BH][T][64]
    unsigned short* __restrict__ Ko,         // [BH][T][64]
    unsigned short* __restrict__ Vo)         // [BH][64][T]
{
    const int K = CDIM;
    __shared__ __align__(16) unsigned short As[128 * 32];
    __shared__ __align__(16) unsigned short Bs[128 * 32];

    const int tid = threadIdx.x;
    const int m0 = blockIdx.y * 128, n0 = blockIdx.x * 128;
    const int w = tid >> 6, lane = tid & 63;
    const int wm = (w >> 1) * 64, wn = (w & 1) * 64;
    const int lm = lane & 15, kg = lane >> 4;

    floatx4 acc[4][4];
    const floatx4 zf = {0.f, 0.f, 0.f, 0.f};
    #pragma unroll
    for (int mt = 0; mt < 4; ++mt)
        #pragma unroll
        for (int nt = 0; nt < 4; ++nt) acc[mt][nt] = zf;

    #pragma unroll 1
    for (int k0 = 0; k0 < K; k0 += 32) {
        __syncthreads();
        #pragma unroll
        for (int i = 0; i < 2; ++i) {
            int ci = i * 256 + tid;                 // 0..511
            GLOAD16(A  + (size_t)(m0 + (ci >> 2)) * K + k0 + (ci & 3) * 8, As + ci * 8);
            GLOAD16(Bt + (size_t)(n0 + (ci >> 2)) * K + k0 + (ci & 3) * 8, Bs + ci * 8);
        }
        __syncthreads();
        short8 af[4], bf[4];
        #pragma unroll
        for (int t = 0; t < 4; ++t) {
            af[t] = *(const short8*)(As + (wm + t * 16 + lm) * 32 + kg * 8);
            bf[t] = *(const short8*)(Bs + (wn + t * 16 + lm) * 32 + kg * 8);
        }
        #pragma unroll
        for (int mt = 0; mt < 4; ++mt)
            #pragma unroll
            for (int nt = 0; nt < 4; ++nt)
                acc[mt][nt] = MFMA_BF16(af[mt], bf[nt], acc[mt][nt]);
    }

    // C layout per 16x16 tile: col = lane&15, row = (lane>>4)*4 + reg
    #pragma unroll
    for (int nt = 0; nt < 4; ++nt) {
        int col = n0 + wn + nt * 16 + lm;       // third is block-uniform
        float bv = bias[col];
        int which = col >> 10;
        int c1 = col & 1023;
        int h = c1 >> 6, d = c1 & 63;
        #pragma unroll
        for (int mt = 0; mt < 4; ++mt) {
            int mbase = m0 + wm + mt * 16 + kg * 4;
            int b = mbase >> 11;
            int t = mbase & 2047;               // t..t+3 contiguous
            int bh = b * NHEAD + h;
            if (which == 2) {
                ushort4 o;
                o.x = f2bf(acc[mt][nt][0] + bv);
                o.y = f2bf(acc[mt][nt][1] + bv);
                o.z = f2bf(acc[mt][nt][2] + bv);
                o.w = f2bf(acc[mt][nt][3] + bv);
                *(ushort4*)(Vo + ((size_t)bh * 64 + d) * SEQ + t) = o;
            } else {
                unsigned short* dst = (which == 0) ? Qo : Ko;
                float qs = (which == 0) ? 0.18033688011112042f : 1.0f; // 0.125*log2e
                #pragma unroll
                for (int r = 0; r < 4; ++r)
                    dst[((size_t)bh * SEQ + t + r) * 64 + d] =
                        f2bf((acc[mt][nt][r] + bv) * qs);
            }
        }
    }
}

// Proj variant: out fp32 [8192][1024] + bias.
__global__ __launch_bounds__(256) void proj_mfma_kernel(
    const unsigned short* __restrict__ A,
    const unsigned short* __restrict__ Bt,
    const float* __restrict__ bias,
    float* __restrict__ out)
{
    const int K = CDIM;
    __shared__ __align__(16) unsigned short As[128 * 32];
    __shared__ __align__(16) unsigned short Bs[128 * 32];

    const int tid = threadIdx.x;
    const int m0 = blockIdx.y * 128, n0 = blockIdx.x * 128;
    const int w = tid >> 6, lane = tid & 63;
    const int wm = (w >> 1) * 64, wn = (w & 1) * 64;
    const int lm = lane & 15, kg = lane >> 4;

    floatx4 acc[4][4];
    const floatx4 zf = {0.f, 0.f, 0.f, 0.f};
    #pragma unroll
    for (int mt = 0; mt < 4; ++mt)
        #pragma unroll
        for (int nt = 0; nt < 4; ++nt) acc[mt][nt] = zf;

    #pragma unroll 1
    for (int k0 = 0; k0 < K; k0 += 32) {
        __syncthreads();
        #pragma unroll
        for (int i = 0; i < 2; ++i) {
            int ci = i * 256 + tid;
            GLOAD16(A  + (size_t)(m0 + (ci >> 2)) * K + k0 + (ci & 3) * 8, As + ci * 8);
            GLOAD16(Bt + (size_t)(n0 + (ci >> 2)) * K + k0 + (ci & 3) * 8, Bs + ci * 8);
        }
        __syncthreads();
        short8 af[4], bf[4];
        #pragma unroll
        for (int t = 0; t < 4; ++t) {
            af[t] = *(const short8*)(As + (wm + t * 16 + lm) * 32 + kg * 8);
            bf[t] = *(const short8*)(Bs + (wn + t * 16 + lm) * 32 + kg * 8);
        }
        #pragma unroll
        for (int mt = 0; mt < 4; ++mt)
            #pragma unroll
            for (int nt = 0; nt < 4; ++nt)
                acc[mt][nt] = MFMA_BF16(af[mt], bf[nt], acc[mt][nt]);
    }

    #pragma unroll
    for (int nt = 0; nt < 4; ++nt) {
        int col = n0 + wn + nt * 16 + lm;
        float bv = bias[col];
        #pragma unroll
        for (int mt = 0; mt < 4; ++mt) {
            int mbase = m0 + wm + mt * 16 + kg * 4;
            #pragma unroll
            for (int r = 0; r < 4; ++r)
                out[(size_t)(mbase + r) * CDIM + col] = acc[mt][nt][r] + bv;
        }
    }
}

// ---------------------------------------------------------------------------
// Flash attention v2: no-max exp2 softmax, S^T trick, padded LDS (stride 72).
// Block = 256 thr = 4 waves, 128 q-rows (32/wave). KV swept in 64-col tiles.
// Q pre-scaled by 0.125*log2e. Q frags live in registers.
// Q,K: [BH][T][64] bf16; V: [BH][64][T] bf16. Out Y: [B][T][C] bf16.
// ---------------------------------------------------------------------------
#define PSTR 72   // padded LDS row stride (shorts): 36 dwords -> 2-way max

__global__ __launch_bounds__(256) void attn_mfma_kernel(
    const unsigned short* __restrict__ Qg,
    const unsigned short* __restrict__ Kg,
    const unsigned short* __restrict__ Vg,
    unsigned short* __restrict__ Y)
{
    __shared__ __align__(16) unsigned short Ks[64 * PSTR];    //  9.2 KB [k][d]
    __shared__ __align__(16) unsigned short Vs[64 * PSTR];    //  9.2 KB [d][k]
    __shared__ __align__(16) unsigned short Ps[128 * PSTR];   // 18.4 KB [q][k]

    const int tid = threadIdx.x, w = tid >> 6, lane = tid & 63;
    const int lm = lane & 15, kg = lane >> 4;
    const int qb = blockIdx.x, bh = blockIdx.y;
    const size_t base = (size_t)bh * SEQ * 64;   // same for Q,K,V buffers

    // Q fragments in registers: qf[nt][c] = Q[qb*128 + w*32 + nt*16 + lm][c*32 + kg*8 ..]
    short8 qf[2][2];
    #pragma unroll
    for (int nt = 0; nt < 2; ++nt)
        #pragma unroll
        for (int c = 0; c < 2; ++c)
            qf[nt][c] = *(const short8*)(
                Qg + base + (size_t)(qb * 128 + w * 32 + nt * 16 + lm) * 64 + c * 32 + kg * 8);

    const floatx4 zf = {0.f, 0.f, 0.f, 0.f};
    floatx4 O[2][4];                 // [q-tile][d-tile]
    #pragma unroll
    for (int mq = 0; mq < 2; ++mq)
        #pragma unroll
        for (int nd = 0; nd < 4; ++nd) O[mq][nd] = zf;
    float lsum[2] = {0.f, 0.f};      // per-lane partial row sums (q = w*32+nt*16+lm)

    #pragma unroll 1
    for (int kb = 0; kb < SEQ / 64; ++kb) {
        __syncthreads();   // all waves done reading Ks/Vs of previous iter
        // stage K tile [k][d] and V tile [d][k], padded stride
        #pragma unroll
        for (int i = 0; i < 2; ++i) {
            int lin = i * 256 + tid;          // 0..511
            int row = lin >> 3;               // 0..63
            int c8  = (lin & 7) * 8;          // 0..56 shorts
            uint4 kv = *(const uint4*)(Kg + base + (size_t)(kb * 64 + row) * 64 + c8);
            *(uint4*)(Ks + row * PSTR + c8) = kv;
            uint4 vv = *(const uint4*)(Vg + base + (size_t)row * SEQ + kb * 64 + c8);
            *(uint4*)(Vs + row * PSTR + c8) = vv;
        }
        __syncthreads();

        // S^T[k][q] = K . Q^T : A = K rows (a-frag), B = Q rows (b-frag)
        // C layout: col = q = lm (within nt), row = k = mt*16 + kg*4 + reg
        floatx4 st[4][2];
        #pragma unroll
        for (int mt = 0; mt < 4; ++mt) { st[mt][0] = zf; st[mt][1] = zf; }
        #pragma unroll
        for (int c = 0; c < 2; ++c)
            #pragma unroll
            for (int mt = 0; mt < 4; ++mt) {
                short8 kf = *(const short8*)(Ks + (mt * 16 + lm) * PSTR + c * 32 + kg * 8);
                st[mt][0] = MFMA_BF16(kf, qf[0][c], st[mt][0]);
                st[mt][1] = MFMA_BF16(kf, qf[1][c], st[mt][1]);
            }

        // P = exp2(S^T); accumulate row sums; pack 4 consecutive k -> b64 write
        #pragma unroll
        for (int mt = 0; mt < 4; ++mt)
            #pragma unroll
            for (int nt = 0; nt < 2; ++nt) {
                float e0 = fast_exp2(st[mt][nt][0]);
                float e1 = fast_exp2(st[mt][nt][1]);
                float e2 = fast_exp2(st[mt][nt][2]);
                float e3 = fast_exp2(st[mt][nt][3]);
                lsum[nt] += (e0 + e1) + (e2 + e3);
                uint2 pk;
                pk.x = pack_bf16(e0, e1);
                pk.y = pack_bf16(e2, e3);
                *(uint2*)(Ps + (w * 32 + nt * 16 + lm) * PSTR + mt * 16 + kg * 4) = pk;
            }
        // no barrier: Ps rows w*32..w*32+31 are wave-private; DS is in-order per wave

        // O[q][d] += P . V : A = P rows [q][k] (a-frag), B = V from Vs[d][k] (b-frag)
        #pragma unroll
        for (int c = 0; c < 2; ++c) {
            short8 pa0 = *(const short8*)(Ps + (w * 32 +      lm) * PSTR + c * 32 + kg * 8);
            short8 pa1 = *(const short8*)(Ps + (w * 32 + 16 + lm) * PSTR + c * 32 + kg * 8);
            #pragma unroll
            for (int nd = 0; nd < 4; ++nd) {
                short8 vb = *(const short8*)(Vs + (nd * 16 + lm) * PSTR + c * 32 + kg * 8);
                O[0][nd] = MFMA_BF16(pa0, vb, O[0][nd]);
                O[1][nd] = MFMA_BF16(pa1, vb, O[1][nd]);
            }
        }
    }

    // finalize row sums: reduce across kg groups (k slices live in kg lanes)
    #pragma unroll
    for (int nt = 0; nt < 2; ++nt) {
        lsum[nt] += __shfl_xor(lsum[nt], 16);
        lsum[nt] += __shfl_xor(lsum[nt], 32);
    }
    // fetch 1/l for O rows (q = w*32 + mq*16 + kg*4 + r lives at lane lm = kg*4+r)
    float linv[2][4];
    #pragma unroll
    for (int mq = 0; mq < 2; ++mq)
        #pragma unroll
        for (int r = 0; r < 4; ++r)
            linv[mq][r] = 1.0f / __shfl(lsum[mq], kg * 4 + r);

    // epilogue: Y[b][t][h*64 + d] bf16
    const int b = bh >> 4, h = bh & 15;
    #pragma unroll
    for (int mq = 0; mq < 2; ++mq)
        #pragma unroll
        for (int r = 0; r < 4; ++r) {
            int t = qb * 128 + w * 32 + mq * 16 + kg * 4 + r;
            #pragma unroll
            for (int nd = 0; nd < 4; ++nd)
                Y[((size_t)(b * SEQ + t)) * CDIM + h * 64 + nd * 16 + lm] =
                    f2bf(O[mq][nd][r] * linv[mq][r]);
        }
}

extern "C" void kernel_launch(void* const* d_in, const int* in_sizes, int n_in,
                              void* d_out, int out_size, void* d_ws, size_t ws_size,
                              hipStream_t stream) {
    const float* x      = (const float*)d_in[0];
    const float* W_attn = (const float*)d_in[1];
    const float* b_attn = (const float*)d_in[2];
    const float* W_proj = (const float*)d_in[3];
    const float* b_proj = (const float*)d_in[4];
    float* out = (float*)d_out;

    // workspace layout (bf16 buffers)
    char* ws = (char*)d_ws;
    unsigned short* xb  = (unsigned short*)(ws);                      // 16.8 MB
    unsigned short* Wat = (unsigned short*)(ws + (size_t)16777216);   //  6.3 MB
    unsigned short* Wpt = (unsigned short*)(ws + (size_t)23068672);   //  2.1 MB
    unsigned short* Qb  = (unsigned short*)(ws + (size_t)25165824);   // 16.8 MB
    unsigned short* Kb  = (unsigned short*)(ws + (size_t)41943040);   // 16.8 MB
    unsigned short* Vtb = (unsigned short*)(ws + (size_t)58720256);   // 16.8 MB
    unsigned short* Yb  = (unsigned short*)(ws + (size_t)75497472);   // 16.8 MB

    // converts
    conv_bf16_kernel<<<dim3(MROWS * CDIM / 1024), 256, 0, stream>>>(x, xb);
    conv_wt_kernel<<<dim3(3 * CDIM / 64, CDIM / 64), 256, 0, stream>>>(
        W_attn, Wat, CDIM, 3 * CDIM);
    conv_wt_kernel<<<dim3(CDIM / 64, CDIM / 64), 256, 0, stream>>>(
        W_proj, Wpt, CDIM, CDIM);

    // QKV projection (Q pre-scaled for exp2 softmax)
    qkv_mfma_kernel<<<dim3(3 * CDIM / 128, MROWS / 128), 256, 0, stream>>>(
        xb, Wat, b_attn, Qb, Kb, Vtb);

    // attention: 128 q-rows per block
    attn_mfma_kernel<<<dim3(SEQ / 128, BH), 256, 0, stream>>>(Qb, Kb, Vtb, Yb);

    // output projection
    proj_mfma_kernel<<<dim3(CDIM / 128, MROWS / 128), 256, 0, stream>>>(
        Yb, Wpt, b_proj, out);
}

// Round 4
// 333.894 us; speedup vs baseline: 5.9100x; 1.1255x over previous
//
#include <hip/hip_runtime.h>

#define BATCH 4
#define SEQ   2048
#define CDIM  1024
#define NHEAD 16
#define HDIM  64
#define BH    (BATCH * NHEAD)   // 64
#define MROWS (BATCH * SEQ)     // 8192

typedef __attribute__((ext_vector_type(8))) short  short8;
typedef __attribute__((ext_vector_type(4))) float  floatx4;

#define MFMA_BF16(a, b, c) __builtin_amdgcn_mfma_f32_16x16x32_bf16((a), (b), (c), 0, 0, 0)

// async global->LDS, 16B per lane (GEMMs only; attn uses padded manual staging)
#define GLOAD16(g, l) __builtin_amdgcn_global_load_lds( \
    (__attribute__((address_space(1))) void*)(g),       \
    (__attribute__((address_space(3))) void*)(l), 16, 0, 0)

__device__ __forceinline__ unsigned short f2bf(float f) {
    union { float f; unsigned u; } v; v.f = f;
    unsigned u = v.u;
    return (unsigned short)((u + 0x7FFFu + ((u >> 16) & 1u)) >> 16);
}

__device__ __forceinline__ float fast_exp2(float x) {
#if __has_builtin(__builtin_amdgcn_exp2f)
    return __builtin_amdgcn_exp2f(x);
#else
    return exp2f(x);
#endif
}

// pack two fp32 -> two bf16, TRUNCATING (1 v_perm). The uniform (1-2^-9)
// downward bias cancels in softmax normalization; residual noise ~2^-8.5
// is far below the bf16 quantization already present.
__device__ __forceinline__ unsigned pack_bf16_trunc(float a, float b) {
    union { float f; unsigned u; } ua, ub;
    ua.f = a; ub.f = b;
    return __builtin_amdgcn_perm(ub.u, ua.u, 0x07060302u);
}

// ---------------------------------------------------------------------------
// fp32 -> bf16 elementwise convert (x). 4 elems/thread.
// ---------------------------------------------------------------------------
__global__ __launch_bounds__(256) void conv_bf16_kernel(
    const float* __restrict__ in, unsigned short* __restrict__ out)
{
    int i = (blockIdx.x * 256 + threadIdx.x) * 4;
    float4 v = *(const float4*)(in + i);
    ushort4 o;
    o.x = f2bf(v.x); o.y = f2bf(v.y); o.z = f2bf(v.z); o.w = f2bf(v.w);
    *(ushort4*)(out + i) = o;
}

// ---------------------------------------------------------------------------
// fp32 [K][N] -> bf16 transposed [N][K] (weights). 64x64 LDS tiles.
// ---------------------------------------------------------------------------
__global__ __launch_bounds__(256) void conv_wt_kernel(
    const float* __restrict__ in, unsigned short* __restrict__ out, int K, int N)
{
    __shared__ float T[64][68];
    const int k0 = blockIdx.y * 64, n0 = blockIdx.x * 64;
    const int tid = threadIdx.x;
    const int r = tid >> 4, c4 = (tid & 15) * 4;
    #pragma unroll
    for (int i = 0; i < 4; ++i) {
        int row = r + i * 16;
        float4 v = *(const float4*)(in + (size_t)(k0 + row) * N + n0 + c4);
        T[row][c4 + 0] = v.x; T[row][c4 + 1] = v.y;
        T[row][c4 + 2] = v.z; T[row][c4 + 3] = v.w;
    }
    __syncthreads();
    #pragma unroll
    for (int i = 0; i < 4; ++i) {
        int nrow = r + i * 16;
        ushort4 o;
        o.x = f2bf(T[c4 + 0][nrow]); o.y = f2bf(T[c4 + 1][nrow]);
        o.z = f2bf(T[c4 + 2][nrow]); o.w = f2bf(T[c4 + 3][nrow]);
        *(ushort4*)(out + (size_t)(n0 + nrow) * K + k0 + c4) = o;
    }
}

// ---------------------------------------------------------------------------
// MFMA GEMM, 128x128 tile, BK=32, 256 thr = 4 waves (2x2), 16x16x32 bf16.
// QKV variant: +bias, Q pre-scaled by 0.125*log2(e) for exp2 softmax,
// scatter Q,K:[BH][T][D], V transposed:[BH][D][T].
// ---------------------------------------------------------------------------
__global__ __launch_bounds__(256) void qkv_mfma_kernel(
    const unsigned short* __restrict__ A,    // xb [8192][1024]
    const unsigned short* __restrict__ Bt,   // Wat [3072][1024]
    const float* __restrict__ bias,          // [3072]
    unsigned short* __restrict__ Qo,         // [BH][T][64]
    unsigned short* __restrict__ Ko,         // [BH][T][64]
    unsigned short* __restrict__ Vo)         // [BH][64][T]
{
    const int K = CDIM;
    __shared__ __align__(16) unsigned short As[128 * 32];
    __shared__ __align__(16) unsigned short Bs[128 * 32];

    const int tid = threadIdx.x;
    const int m0 = blockIdx.y * 128, n0 = blockIdx.x * 128;
    const int w = tid >> 6, lane = tid & 63;
    const int wm = (w >> 1) * 64, wn = (w & 1) * 64;
    const int lm = lane & 15, kg = lane >> 4;

    floatx4 acc[4][4];
    const floatx4 zf = {0.f, 0.f, 0.f, 0.f};
    #pragma unroll
    for (int mt = 0; mt < 4; ++mt)
        #pragma unroll
        for (int nt = 0; nt < 4; ++nt) acc[mt][nt] = zf;

    #pragma unroll 1
    for (int k0 = 0; k0 < K; k0 += 32) {
        __syncthreads();
        #pragma unroll
        for (int i = 0; i < 2; ++i) {
            int ci = i * 256 + tid;                 // 0..511
            GLOAD16(A  + (size_t)(m0 + (ci >> 2)) * K + k0 + (ci & 3) * 8, As + ci * 8);
            GLOAD16(Bt + (size_t)(n0 + (ci >> 2)) * K + k0 + (ci & 3) * 8, Bs + ci * 8);
        }
        __syncthreads();
        short8 af[4], bf[4];
        #pragma unroll
        for (int t = 0; t < 4; ++t) {
            af[t] = *(const short8*)(As + (wm + t * 16 + lm) * 32 + kg * 8);
            bf[t] = *(const short8*)(Bs + (wn + t * 16 + lm) * 32 + kg * 8);
        }
        #pragma unroll
        for (int mt = 0; mt < 4; ++mt)
            #pragma unroll
            for (int nt = 0; nt < 4; ++nt)
                acc[mt][nt] = MFMA_BF16(af[mt], bf[nt], acc[mt][nt]);
    }

    // C layout per 16x16 tile: col = lane&15, row = (lane>>4)*4 + reg
    #pragma unroll
    for (int nt = 0; nt < 4; ++nt) {
        int col = n0 + wn + nt * 16 + lm;       // third is block-uniform
        float bv = bias[col];
        int which = col >> 10;
        int c1 = col & 1023;
        int h = c1 >> 6, d = c1 & 63;
        #pragma unroll
        for (int mt = 0; mt < 4; ++mt) {
            int mbase = m0 + wm + mt * 16 + kg * 4;
            int b = mbase >> 11;
            int t = mbase & 2047;               // t..t+3 contiguous
            int bh = b * NHEAD + h;
            if (which == 2) {
                ushort4 o;
                o.x = f2bf(acc[mt][nt][0] + bv);
                o.y = f2bf(acc[mt][nt][1] + bv);
                o.z = f2bf(acc[mt][nt][2] + bv);
                o.w = f2bf(acc[mt][nt][3] + bv);
                *(ushort4*)(Vo + ((size_t)bh * 64 + d) * SEQ + t) = o;
            } else {
                unsigned short* dst = (which == 0) ? Qo : Ko;
                float qs = (which == 0) ? 0.18033688011112042f : 1.0f; // 0.125*log2e
                #pragma unroll
                for (int r = 0; r < 4; ++r)
                    dst[((size_t)bh * SEQ + t + r) * 64 + d] =
                        f2bf((acc[mt][nt][r] + bv) * qs);
            }
        }
    }
}

// Proj variant: out fp32 [8192][1024] + bias.
__global__ __launch_bounds__(256) void proj_mfma_kernel(
    const unsigned short* __restrict__ A,
    const unsigned short* __restrict__ Bt,
    const float* __restrict__ bias,
    float* __restrict__ out)
{
    const int K = CDIM;
    __shared__ __align__(16) unsigned short As[128 * 32];
    __shared__ __align__(16) unsigned short Bs[128 * 32];

    const int tid = threadIdx.x;
    const int m0 = blockIdx.y * 128, n0 = blockIdx.x * 128;
    const int w = tid >> 6, lane = tid & 63;
    const int wm = (w >> 1) * 64, wn = (w & 1) * 64;
    const int lm = lane & 15, kg = lane >> 4;

    floatx4 acc[4][4];
    const floatx4 zf = {0.f, 0.f, 0.f, 0.f};
    #pragma unroll
    for (int mt = 0; mt < 4; ++mt)
        #pragma unroll
        for (int nt = 0; nt < 4; ++nt) acc[mt][nt] = zf;

    #pragma unroll 1
    for (int k0 = 0; k0 < K; k0 += 32) {
        __syncthreads();
        #pragma unroll
        for (int i = 0; i < 2; ++i) {
            int ci = i * 256 + tid;
            GLOAD16(A  + (size_t)(m0 + (ci >> 2)) * K + k0 + (ci & 3) * 8, As + ci * 8);
            GLOAD16(Bt + (size_t)(n0 + (ci >> 2)) * K + k0 + (ci & 3) * 8, Bs + ci * 8);
        }
        __syncthreads();
        short8 af[4], bf[4];
        #pragma unroll
        for (int t = 0; t < 4; ++t) {
            af[t] = *(const short8*)(As + (wm + t * 16 + lm) * 32 + kg * 8);
            bf[t] = *(const short8*)(Bs + (wn + t * 16 + lm) * 32 + kg * 8);
        }
        #pragma unroll
        for (int mt = 0; mt < 4; ++mt)
            #pragma unroll
            for (int nt = 0; nt < 4; ++nt)
                acc[mt][nt] = MFMA_BF16(af[mt], bf[nt], acc[mt][nt]);
    }

    #pragma unroll
    for (int nt = 0; nt < 4; ++nt) {
        int col = n0 + wn + nt * 16 + lm;
        float bv = bias[col];
        #pragma unroll
        for (int mt = 0; mt < 4; ++mt) {
            int mbase = m0 + wm + mt * 16 + kg * 4;
            #pragma unroll
            for (int r = 0; r < 4; ++r)
                out[(size_t)(mbase + r) * CDIM + col] = acc[mt][nt][r] + bv;
        }
    }
}

// ---------------------------------------------------------------------------
// Flash attention v3: 256 q-rows/block, 64 q-rows/wave (amortizes K/V frag
// reads 2x vs v2). No-max exp2 softmax, S^T trick, padded LDS stride 72.
// Q pre-scaled by 0.125*log2e. Q frags in registers.
// Q,K: [BH][T][64] bf16; V: [BH][64][T] bf16. Out Y: [B][T][C] bf16.
// ---------------------------------------------------------------------------
#define PSTR 72   // padded LDS row stride (shorts): 36 dwords -> 2-way max

__global__ __launch_bounds__(256) void attn_mfma_kernel(
    const unsigned short* __restrict__ Qg,
    const unsigned short* __restrict__ Kg,
    const unsigned short* __restrict__ Vg,
    unsigned short* __restrict__ Y)
{
    __shared__ __align__(16) unsigned short Ks[64 * PSTR];     //  9.2 KB [k][d]
    __shared__ __align__(16) unsigned short Vs[64 * PSTR];     //  9.2 KB [d][k]
    __shared__ __align__(16) unsigned short Ps[256 * PSTR];    // 36.9 KB [q][k]

    const int tid = threadIdx.x, w = tid >> 6, lane = tid & 63;
    const int lm = lane & 15, kg = lane >> 4;
    const int qb = blockIdx.x, bh = blockIdx.y;
    const size_t base = (size_t)bh * SEQ * 64;   // same for Q,K,V buffers

    // Q fragments in registers: qf[nt][c], q-row = qb*256 + w*64 + nt*16 + lm
    short8 qf[4][2];
    #pragma unroll
    for (int nt = 0; nt < 4; ++nt)
        #pragma unroll
        for (int c = 0; c < 2; ++c)
            qf[nt][c] = *(const short8*)(
                Qg + base + (size_t)(qb * 256 + w * 64 + nt * 16 + lm) * 64 + c * 32 + kg * 8);

    const floatx4 zf = {0.f, 0.f, 0.f, 0.f};
    floatx4 O[4][4];                 // [q-tile][d-tile]
    #pragma unroll
    for (int mq = 0; mq < 4; ++mq)
        #pragma unroll
        for (int nd = 0; nd < 4; ++nd) O[mq][nd] = zf;
    float lsum[4] = {0.f, 0.f, 0.f, 0.f};   // partial row sums, q = w*64+nt*16+lm

    #pragma unroll 1
    for (int kb = 0; kb < SEQ / 64; ++kb) {
        __syncthreads();   // all waves done reading Ks/Vs of previous iter
        // stage K tile [k][d] and V tile [d][k], padded stride
        #pragma unroll
        for (int i = 0; i < 2; ++i) {
            int lin = i * 256 + tid;          // 0..511
            int row = lin >> 3;               // 0..63
            int c8  = (lin & 7) * 8;          // 0..56 shorts
            uint4 kv = *(const uint4*)(Kg + base + (size_t)(kb * 64 + row) * 64 + c8);
            *(uint4*)(Ks + row * PSTR + c8) = kv;
            uint4 vv = *(const uint4*)(Vg + base + (size_t)row * SEQ + kb * 64 + c8);
            *(uint4*)(Vs + row * PSTR + c8) = vv;
        }
        __syncthreads();

        // S^T[k][q] = K . Q^T per 16-k slab: compute, exp2, pack, write to Ps.
        // C layout: col = q = lm (within nt), row = k = mt*16 + kg*4 + reg
        #pragma unroll
        for (int mt = 0; mt < 4; ++mt) {
            floatx4 st[4];
            #pragma unroll
            for (int nt = 0; nt < 4; ++nt) st[nt] = zf;
            #pragma unroll
            for (int c = 0; c < 2; ++c) {
                short8 kf = *(const short8*)(Ks + (mt * 16 + lm) * PSTR + c * 32 + kg * 8);
                #pragma unroll
                for (int nt = 0; nt < 4; ++nt)
                    st[nt] = MFMA_BF16(kf, qf[nt][c], st[nt]);
            }
            #pragma unroll
            for (int nt = 0; nt < 4; ++nt) {
                float e0 = fast_exp2(st[nt][0]);
                float e1 = fast_exp2(st[nt][1]);
                float e2 = fast_exp2(st[nt][2]);
                float e3 = fast_exp2(st[nt][3]);
                lsum[nt] += (e0 + e1) + (e2 + e3);
                uint2 pk;
                pk.x = pack_bf16_trunc(e0, e1);
                pk.y = pack_bf16_trunc(e2, e3);
                *(uint2*)(Ps + (w * 64 + nt * 16 + lm) * PSTR + mt * 16 + kg * 4) = pk;
            }
        }
        // no barrier: Ps rows w*64..w*64+63 are wave-private; DS in-order per wave

        // O[q][d] += P . V : A = P rows [q][k], B = V from Vs[d][k]
        #pragma unroll
        for (int c = 0; c < 2; ++c) {
            short8 pa[4];
            #pragma unroll
            for (int mq = 0; mq < 4; ++mq)
                pa[mq] = *(const short8*)(Ps + (w * 64 + mq * 16 + lm) * PSTR + c * 32 + kg * 8);
            #pragma unroll
            for (int nd = 0; nd < 4; ++nd) {
                short8 vb = *(const short8*)(Vs + (nd * 16 + lm) * PSTR + c * 32 + kg * 8);
                #pragma unroll
                for (int mq = 0; mq < 4; ++mq)
                    O[mq][nd] = MFMA_BF16(pa[mq], vb, O[mq][nd]);
            }
        }
    }

    // finalize row sums: reduce across kg groups (k slices live in kg lanes)
    #pragma unroll
    for (int nt = 0; nt < 4; ++nt) {
        lsum[nt] += __shfl_xor(lsum[nt], 16);
        lsum[nt] += __shfl_xor(lsum[nt], 32);
    }
    // 1/l for O rows (q = w*64 + mq*16 + kg*4 + r lives at lane lm = kg*4+r)
    float linv[4][4];
    #pragma unroll
    for (int mq = 0; mq < 4; ++mq)
        #pragma unroll
        for (int r = 0; r < 4; ++r)
            linv[mq][r] = 1.0f / __shfl(lsum[mq], kg * 4 + r);

    // epilogue: Y[b][t][h*64 + d] bf16
    const int b = bh >> 4, h = bh & 15;
    #pragma unroll
    for (int mq = 0; mq < 4; ++mq)
        #pragma unroll
        for (int r = 0; r < 4; ++r) {
            int t = qb * 256 + w * 64 + mq * 16 + kg * 4 + r;
            #pragma unroll
            for (int nd = 0; nd < 4; ++nd)
                Y[((size_t)(b * SEQ + t)) * CDIM + h * 64 + nd * 16 + lm] =
                    f2bf(O[mq][nd][r] * linv[mq][r]);
        }
}

extern "C" void kernel_launch(void* const* d_in, const int* in_sizes, int n_in,
                              void* d_out, int out_size, void* d_ws, size_t ws_size,
                              hipStream_t stream) {
    const float* x      = (const float*)d_in[0];
    const float* W_attn = (const float*)d_in[1];
    const float* b_attn = (const float*)d_in[2];
    const float* W_proj = (const float*)d_in[3];
    const float* b_proj = (const float*)d_in[4];
    float* out = (float*)d_out;

    // workspace layout (bf16 buffers)
    char* ws = (char*)d_ws;
    unsigned short* xb  = (unsigned short*)(ws);                      // 16.8 MB
    unsigned short* Wat = (unsigned short*)(ws + (size_t)16777216);   //  6.3 MB
    unsigned short* Wpt = (unsigned short*)(ws + (size_t)23068672);   //  2.1 MB
    unsigned short* Qb  = (unsigned short*)(ws + (size_t)25165824);   // 16.8 MB
    unsigned short* Kb  = (unsigned short*)(ws + (size_t)41943040);   // 16.8 MB
    unsigned short* Vtb = (unsigned short*)(ws + (size_t)58720256);   // 16.8 MB
    unsigned short* Yb  = (unsigned short*)(ws + (size_t)75497472);   // 16.8 MB

    // converts
    conv_bf16_kernel<<<dim3(MROWS * CDIM / 1024), 256, 0, stream>>>(x, xb);
    conv_wt_kernel<<<dim3(3 * CDIM / 64, CDIM / 64), 256, 0, stream>>>(
        W_attn, Wat, CDIM, 3 * CDIM);
    conv_wt_kernel<<<dim3(CDIM / 64, CDIM / 64), 256, 0, stream>>>(
        W_proj, Wpt, CDIM, CDIM);

    // QKV projection (Q pre-scaled for exp2 softmax)
    qkv_mfma_kernel<<<dim3(3 * CDIM / 128, MROWS / 128), 256, 0, stream>>>(
        xb, Wat, b_attn, Qb, Kb, Vtb);

    // attention: 256 q-rows per block
    attn_mfma_kernel<<<dim3(SEQ / 256, BH), 256, 0, stream>>>(Qb, Kb, Vtb, Yb);

    // output projection
    proj_mfma_kernel<<<dim3(CDIM / 128, MROWS / 128), 256, 0, stream>>>(
        Yb, Wpt, b_proj, out);
}